// Round 14
// baseline (267.315 us; speedup 1.0000x reference)
//
#include <hip/hip_runtime.h>

#define N_IN 64
#define N_H  128
#define N_G  64
#define HP   4    // node partitions (LDS histogram / fill)
#define HC   64   // edge chunks
#define YSTRIDE 132

// XOR swizzle for bf16 LDS tiles, applied to k in groups of 8 bf16 (16B).
#define SWZB(r) (((r) & 7) << 3)

typedef unsigned int   uint32;
typedef unsigned short ushort16;
typedef unsigned char  uchar8;
typedef float floatx2 __attribute__((ext_vector_type(2)));
typedef short bf16x8 __attribute__((ext_vector_type(8)));
typedef float f32x4  __attribute__((ext_vector_type(4)));

#define FP8_SCALE    32.0f
#define FP8_INVSCALE 0.03125f

#if defined(__has_builtin)
#if __has_builtin(__builtin_amdgcn_cvt_pk_f32_fp8) && __has_builtin(__builtin_amdgcn_cvt_pk_fp8_f32)
#define HW_FP8 1
#endif
#endif

__device__ __forceinline__ float bf2f(ushort16 u) {
    union { uint32 i; float f; } x; x.i = ((uint32)u) << 16; return x.f;
}
__device__ __forceinline__ ushort16 f2bf(float f) {   // round-to-nearest-even
    union { float f; uint32 i; } x; x.f = f;
    uint32 r = x.i + 0x7FFFu + ((x.i >> 16) & 1u);
    return (ushort16)(r >> 16);
}

#ifndef HW_FP8
__device__ __forceinline__ uint32 f2e4m3(float x) {
    union { float f; uint32 i; } v; v.f = x;
    uint32 s = (v.i >> 24) & 0x80u;
    uint32 a = v.i & 0x7FFFFFFFu;
    if (a < 0x3C000000u) return s;
    uint32 r = a + 0x0007FFFFu + ((a >> 20) & 1u);
    int e = (int)(r >> 23) - 120;
    if (e <= 0) return s;
    if (e > 15) return s | 0x7Eu;
    return s | ((uint32)e << 3) | ((r >> 20) & 7u);
}
__device__ __forceinline__ floatx2 e4m3word(uint32 u, bool hi) {
    floatx2 o;
    uint32 w = hi ? (u >> 16) : u;
    #pragma unroll
    for (int k = 0; k < 2; ++k) {
        uint32 b = (w >> (8 * k)) & 0xFFu;
        uint32 m = b & 0x7Fu;
        union { uint32 i; float f; } x;
        x.i = ((b & 0x80u) << 24) | ((m << 20) + 0x3C000000u);
        o[k] = m ? x.f : 0.f;
    }
    return o;
}
#endif

__device__ __forceinline__ floatx2 fp8lo(uint32 u) {
#ifdef HW_FP8
    return __builtin_amdgcn_cvt_pk_f32_fp8((int)u, false);
#else
    return e4m3word(u, false);
#endif
}
__device__ __forceinline__ floatx2 fp8hi(uint32 u) {
#ifdef HW_FP8
    return __builtin_amdgcn_cvt_pk_f32_fp8((int)u, true);
#else
    return e4m3word(u, true);
#endif
}

__device__ __forceinline__ uint32 pack4fp8(float o0, float o1, float o2, float o3) {
#ifdef HW_FP8
    int r = __builtin_amdgcn_cvt_pk_fp8_f32(o0, o1, 0, false);
    r     = __builtin_amdgcn_cvt_pk_fp8_f32(o2, o3, r, true);
    return (uint32)r;
#else
    return f2e4m3(o0) | (f2e4m3(o1) << 8) | (f2e4m3(o2) << 16) | (f2e4m3(o3) << 24);
#endif
}

// ---------------- graph prep ----------------
// hist + wprep fused: blocks [0, HP*HC) histogram; blocks >= HP*HC do
// workspace zeroing + W transposes (replaces wprep + hipMemsetAsync).
__global__ __launch_bounds__(1024) void hist_kernel(const int* __restrict__ src,
        const int* __restrict__ dst, ushort16* __restrict__ part_cnt,
        const float* __restrict__ W1, const float* __restrict__ W2,
        ushort16* __restrict__ W1T, ushort16* __restrict__ W2T,
        int* __restrict__ zbase, int zero_words,
        int N, int E, int npp, int ec) {
    extern __shared__ int cnt[];
    int b = blockIdx.x;
    if (b >= HP * HC) {
        int base = (b - HP * HC) * 1024 + threadIdx.x;
        for (int t = base; t < zero_words; t += 8 * 1024) zbase[t] = 0;
        for (int t = base; t < 128 * 128; t += 8 * 1024) {
            int j = t >> 7, k = t & 127;
            W2T[j * 128 + k] = f2bf(W2[k * 128 + j]);
        }
        for (int t = base; t < 128 * 64; t += 8 * 1024) {
            int j = t >> 6, k = t & 63;
            W1T[j * 64 + k] = f2bf(W1[k * 128 + j]);
        }
        return;
    }
    int p = b & (HP - 1);
    int c = b >> 2;
    int nlo = p * npp;
    int nhi = min(nlo + npp, N);
    int nn = nhi - nlo;
    if (nn <= 0) return;
    int tid = threadIdx.x;
    for (int i = tid; i < nn; i += 1024) cnt[i] = 0;
    __syncthreads();
    int elo = c * ec, ehi = min(elo + ec, E);
    for (int e = elo + tid; e < ehi; e += 1024) {
        int s = src[e];
        unsigned so = (unsigned)(s - nlo);
        if (so < (unsigned)nn) atomicAdd(&cnt[so], 1);
        int d = dst[e];
        unsigned dof = (unsigned)(d - nlo);
        if (dof < (unsigned)nn) atomicAdd(&cnt[dof], 1 << 16);
    }
    __syncthreads();
    for (int i = tid; i < nn; i += 1024) {
        int v = cnt[i];
        part_cnt[(size_t)c * N + nlo + i] =
            (ushort16)((v & 0xFF) | ((v >> 8) & 0xFF00));
    }
}

// reduce_norm + scan_partial fused: also emits per-block deg_in sums (bsum).
__global__ __launch_bounds__(256) void reduce_norm_kernel(const ushort16* __restrict__ part_cnt,
        uchar8* __restrict__ pre, const int* __restrict__ gid,
        float* __restrict__ iso, float* __restrict__ isi, int* __restrict__ deg_in,
        int* __restrict__ gstart, int* __restrict__ gend, int* __restrict__ bsum, int N) {
    int n = blockIdx.x * 256 + threadIdx.x;
    int si = 0;
    if (n < N) {
        int so = 0;
        #pragma unroll
        for (int c = 0; c < HC; ++c) {
            int v = part_cnt[(size_t)c * N + n];
            so += v & 0xFF;
            pre[(size_t)c * N + n] = (uchar8)si;
            si += v >> 8;
        }
        iso[n] = rsqrtf((float)max(so, 1));
        isi[n] = rsqrtf((float)max(si, 1));
        deg_in[n] = si;
        int g = gid[n];
        if (n == 0 || gid[n - 1] != g) gstart[g] = n;
        if (n == N - 1 || gid[n + 1] != g) gend[g] = n + 1;
    }
    // block-reduce si -> bsum[blockIdx.x]
    int lane = threadIdx.x & 63, wv = threadIdx.x >> 6;
    int s = si;
    #pragma unroll
    for (int off = 1; off < 64; off <<= 1) s += __shfl_xor(s, off);
    __shared__ int ws[4];
    if (lane == 0) ws[wv] = s;
    __syncthreads();
    if (threadIdx.x == 0) bsum[blockIdx.x] = ws[0] + ws[1] + ws[2] + ws[3];
}

// scan_write (with self-computed bsum prefix) + scale_h fused.
__global__ __launch_bounds__(256) void scanw_scaleh_kernel(const int* __restrict__ deg_in,
        const int* __restrict__ bsum, int* __restrict__ row_ptr,
        const float* __restrict__ h, const float* __restrict__ iso,
        uchar8* __restrict__ hs8, int nb2, int N) {
    int b = blockIdx.x;
    int tid = threadIdx.x;
    if (b < nb2) {
        int lane = tid & 63, wv = tid >> 6;
        // base = sum of bsum[0..b)
        int acc = 0;
        for (int i = tid; i < b; i += 256) acc += bsum[i];
        #pragma unroll
        for (int off = 1; off < 64; off <<= 1) acc += __shfl_xor(acc, off);
        __shared__ int wsum[4];
        if (lane == 0) wsum[wv] = acc;
        __syncthreads();
        int base = wsum[0] + wsum[1] + wsum[2] + wsum[3];
        // 256-thread inclusive scan of deg_in chunk
        int n = b * 256 + tid;
        int v = (n < N) ? deg_in[n] : 0;
        int s = v;
        #pragma unroll
        for (int off = 1; off < 64; off <<= 1) {
            int t2 = __shfl_up(s, off);
            if (lane >= off) s += t2;
        }
        __shared__ int winc[4];
        if (lane == 63) winc[wv] = s;
        __syncthreads();
        int wpre = 0;
        #pragma unroll
        for (int k = 0; k < 4; ++k) wpre += (k < wv) ? winc[k] : 0;
        if (n < N) row_ptr[n] = base + wpre + s - v;
        if (n == N - 1) row_ptr[N] = base + wpre + s;
    } else {
        // scale_h: hs8[n][j] = fp8(h[n][j] * iso[n] * 32), 8 elems/thread
        int t = (b - nb2) * 256 + tid;
        int base = t * 8;
        if (base >= N * N_IN) return;
        int n = base >> 6;
        float sc = iso[n] * FP8_SCALE;
        float4 a = *(const float4*)&h[base];
        float4 bb = *(const float4*)&h[base + 4];
        uint2 pk;
        pk.x = pack4fp8(a.x * sc, a.y * sc, a.z * sc, a.w * sc);
        pk.y = pack4fp8(bb.x * sc, bb.y * sc, bb.z * sc, bb.w * sc);
        *(uint2*)&hs8[base] = pk;
    }
}

__global__ __launch_bounds__(1024) void fill_kernel(const int* __restrict__ src,
        const int* __restrict__ dst, const int* __restrict__ row_ptr,
        const uchar8* __restrict__ pre, int* __restrict__ col,
        int N, int E, int npp, int ec) {
    extern __shared__ int cur[];
    int p = blockIdx.x & (HP - 1);
    int c = blockIdx.x >> 2;
    int nlo = p * npp;
    int nhi = min(nlo + npp, N);
    int nn = nhi - nlo;
    if (nn <= 0) return;
    int tid = threadIdx.x;
    for (int i = tid; i < nn; i += 1024)
        cur[i] = row_ptr[nlo + i] + (int)pre[(size_t)c * N + nlo + i];
    __syncthreads();
    int elo = c * ec, ehi = min(elo + ec, E);
    for (int e = elo + tid; e < ehi; e += 1024) {
        int d = dst[e];
        unsigned off = (unsigned)(d - nlo);
        if (off < (unsigned)nn) {
            int slot = atomicAdd(&cur[off], 1);
            col[slot] = src[e];
        }
    }
}

// ---------------- gathers ----------------
__global__ __launch_bounds__(256) void gather1_kernel(const uchar8* __restrict__ hs8,
        const int* __restrict__ row_ptr, const int* __restrict__ col,
        uint32* __restrict__ agg1w, int N) {
    int wave = __builtin_amdgcn_readfirstlane(threadIdx.x >> 6);
    int lane = threadIdx.x & 63;
    int qd = lane >> 4, l16 = lane & 15;
    int n = blockIdx.x * 4 + wave;
    if (n >= N) return;
    int p0 = row_ptr[n], p1 = row_ptr[n + 1];
    uint32 lofs = (uint32)l16 * 4;
    float a0 = 0.f, a1 = 0.f, a2 = 0.f, a3 = 0.f;
    for (int pb = p0; pb < p1; pb += 64) {
        int cnt = min(64, p1 - pb);
        uint32 cvoff = ((uint32)col[min(pb + lane, p1 - 1)]) << 6;
        int i0 = 0;
        for (; i0 + 16 <= cnt; i0 += 16) {   // full batch: no clamp, no mask
            uint32 off[4], u[4];
            #pragma unroll
            for (int i = 0; i < 4; ++i)
                off[i] = __shfl(cvoff, i0 + 4 * i + qd);
            #pragma unroll
            for (int i = 0; i < 4; ++i)
                u[i] = *(const uint32*)((const char*)hs8 + (off[i] + lofs));
            #pragma unroll
            for (int i = 0; i < 4; ++i) {
                floatx2 dlo = fp8lo(u[i]), dhi = fp8hi(u[i]);
                a0 += dlo.x; a1 += dlo.y; a2 += dhi.x; a3 += dhi.y;
            }
        }
        if (i0 < cnt) {                       // tail: clamp + mask
            uint32 off[4], u[4];
            float w[4];
            #pragma unroll
            for (int i = 0; i < 4; ++i) {
                int q = i0 + 4 * i + qd;
                off[i] = __shfl(cvoff, min(q, cnt - 1));
                w[i] = (q < cnt) ? 1.f : 0.f;
            }
            #pragma unroll
            for (int i = 0; i < 4; ++i)
                u[i] = *(const uint32*)((const char*)hs8 + (off[i] + lofs));
            #pragma unroll
            for (int i = 0; i < 4; ++i) {
                floatx2 dlo = fp8lo(u[i]), dhi = fp8hi(u[i]);
                a0 = fmaf(dlo.x, w[i], a0);
                a1 = fmaf(dlo.y, w[i], a1);
                a2 = fmaf(dhi.x, w[i], a2);
                a3 = fmaf(dhi.y, w[i], a3);
            }
        }
    }
    a0 += __shfl_xor(a0, 16); a0 += __shfl_xor(a0, 32);
    a1 += __shfl_xor(a1, 16); a1 += __shfl_xor(a1, 32);
    a2 += __shfl_xor(a2, 16); a2 += __shfl_xor(a2, 32);
    a3 += __shfl_xor(a3, 16); a3 += __shfl_xor(a3, 32);
    if (lane < 16) {
        a0 *= FP8_INVSCALE; a1 *= FP8_INVSCALE; a2 *= FP8_INVSCALE; a3 *= FP8_INVSCALE;
        uint32 w0 = (uint32)f2bf(a0) | ((uint32)f2bf(a1) << 16);
        uint32 w1 = (uint32)f2bf(a2) | ((uint32)f2bf(a3) << 16);
        *(uint2*)&agg1w[(size_t)n * 32 + l16 * 2] = uint2{w0, w1};
    }
}

__global__ __launch_bounds__(256) void gather2_kernel(const uchar8* __restrict__ h18,
        const int* __restrict__ row_ptr, const int* __restrict__ col,
        uint32* __restrict__ agg2w, int N) {
    int wave = __builtin_amdgcn_readfirstlane(threadIdx.x >> 6);
    int lane = threadIdx.x & 63;
    int half = lane >> 5, l32 = lane & 31;
    int n = blockIdx.x * 4 + wave;
    if (n >= N) return;
    int p0 = row_ptr[n], p1 = row_ptr[n + 1];
    uint32 lofs = (uint32)l32 * 4;
    float a0 = 0.f, a1 = 0.f, a2 = 0.f, a3 = 0.f;
    for (int pb = p0; pb < p1; pb += 64) {
        int cnt = min(64, p1 - pb);
        uint32 cvoff = ((uint32)col[min(pb + lane, p1 - 1)]) << 7;
        int i0 = 0;
        for (; i0 + 16 <= cnt; i0 += 16) {   // full batch: 8 pairs, no clamp/mask
            uint32 off[8], u[8];
            #pragma unroll
            for (int i = 0; i < 8; ++i)
                off[i] = __shfl(cvoff, i0 + 2 * i + half);
            #pragma unroll
            for (int i = 0; i < 8; ++i)
                u[i] = *(const uint32*)((const char*)h18 + (off[i] + lofs));
            #pragma unroll
            for (int i = 0; i < 8; ++i) {
                floatx2 dlo = fp8lo(u[i]), dhi = fp8hi(u[i]);
                a0 += dlo.x; a1 += dlo.y; a2 += dhi.x; a3 += dhi.y;
            }
        }
        if (i0 < cnt) {                       // tail
            uint32 off[8], u[8];
            float w[8];
            #pragma unroll
            for (int i = 0; i < 8; ++i) {
                int q = i0 + 2 * i + half;
                off[i] = __shfl(cvoff, min(q, cnt - 1));
                w[i] = (q < cnt) ? 1.f : 0.f;
            }
            #pragma unroll
            for (int i = 0; i < 8; ++i)
                u[i] = *(const uint32*)((const char*)h18 + (off[i] + lofs));
            #pragma unroll
            for (int i = 0; i < 8; ++i) {
                floatx2 dlo = fp8lo(u[i]), dhi = fp8hi(u[i]);
                a0 = fmaf(dlo.x, w[i], a0);
                a1 = fmaf(dlo.y, w[i], a1);
                a2 = fmaf(dhi.x, w[i], a2);
                a3 = fmaf(dhi.y, w[i], a3);
            }
        }
    }
    a0 += __shfl_xor(a0, 32);
    a1 += __shfl_xor(a1, 32);
    a2 += __shfl_xor(a2, 32);
    a3 += __shfl_xor(a3, 32);
    if (half == 0) {
        a0 *= FP8_INVSCALE; a1 *= FP8_INVSCALE; a2 *= FP8_INVSCALE; a3 *= FP8_INVSCALE;
        uint32 w0 = (uint32)f2bf(a0) | ((uint32)f2bf(a1) << 16);
        uint32 w1 = (uint32)f2bf(a2) | ((uint32)f2bf(a3) << 16);
        *(uint2*)&agg2w[(size_t)n * 64 + l32 * 2] = uint2{w0, w1};
    }
}

// ---------------- MFMA matmuls ----------------
__global__ __launch_bounds__(512) void mm1_kernel(const ushort16* __restrict__ agg1bf,
        const ushort16* __restrict__ W1T, const float* __restrict__ b1,
        const float* __restrict__ isi, const float* __restrict__ iso,
        uchar8* __restrict__ h18, int N) {
    __shared__ union {
        struct { ushort16 A[128 * 64]; ushort16 W[128 * 64]; } st;
        float Y[128 * YSTRIDE];
    } u;
    __shared__ float ISI[128], ISO[128];
    int t = threadIdx.x;
    int n0 = blockIdx.x * 128;
    {
        int r = t >> 2;
        int k0 = (t & 3) * 16;
        bool valid = (n0 + r) < N;
        const uint4* ga = (const uint4*)(agg1bf + (size_t)(n0 + r) * 64 + k0);
        const uint4* gw = (const uint4*)(W1T + (size_t)r * 64 + k0);
        #pragma unroll
        for (int q = 0; q < 2; ++q) {
            uint4 va = valid ? ga[q] : uint4{0, 0, 0, 0};
            uint4 vw = gw[q];
            int kg = k0 + q * 8;
            *(uint4*)&u.st.A[r * 64 + (kg ^ SWZB(r))] = va;
            *(uint4*)&u.st.W[r * 64 + (kg ^ SWZB(r))] = vw;
        }
        if (t < 128) {
            ISI[t] = (n0 + t < N) ? isi[n0 + t] : 0.f;
            ISO[t] = (n0 + t < N) ? iso[n0 + t] * FP8_SCALE : 0.f;
        }
    }
    __syncthreads();
    int w = __builtin_amdgcn_readfirstlane(t >> 6);
    int l = t & 63, l15 = l & 15, lhi = l >> 4;
    int jcol = w * 16 + l15;
    float b1j = b1[jcol];
    f32x4 acc[8] = {};
    #pragma unroll
    for (int kk = 0; kk < 2; ++kk) {
        int kb = kk * 32 + lhi * 8;
        bf16x8 bf = *(bf16x8*)&u.st.W[jcol * 64 + (kb ^ SWZB(jcol))];
        #pragma unroll
        for (int tm = 0; tm < 8; ++tm) {
            int row = tm * 16 + l15;
            bf16x8 af = *(bf16x8*)&u.st.A[row * 64 + (kb ^ SWZB(row))];
            acc[tm] = __builtin_amdgcn_mfma_f32_16x16x32_bf16(af, bf, acc[tm], 0, 0, 0);
        }
    }
    __syncthreads();
    #pragma unroll
    for (int tm = 0; tm < 8; ++tm) {
        #pragma unroll
        for (int i = 0; i < 4; ++i) {
            int m = tm * 16 + lhi * 4 + i;
            u.Y[m * YSTRIDE + jcol] =
                fmaxf(fmaf(acc[tm][i], ISI[m], b1j), 0.f) * ISO[m];
        }
    }
    __syncthreads();
    {
        int r = t >> 2;
        int c0 = (t & 3) * 32;
        if (n0 + r < N) {
            uint32 b[8];
            #pragma unroll
            for (int q = 0; q < 8; ++q) {
                float4 y4 = *(float4*)&u.Y[r * YSTRIDE + c0 + q * 4];
                b[q] = pack4fp8(y4.x, y4.y, y4.z, y4.w);
            }
            uchar8* dstp = h18 + (size_t)(n0 + r) * 128 + c0;
            *(uint4*)dstp        = uint4{b[0], b[1], b[2], b[3]};
            *(uint4*)(dstp + 16) = uint4{b[4], b[5], b[6], b[7]};
        }
    }
}

// mm2 + fused final readout (last-block pattern; done counter in zeroed region).
__global__ __launch_bounds__(512) void mm2_kernel(const uint32* __restrict__ agg2bf,
        const ushort16* __restrict__ W2T, const float* __restrict__ b2,
        const float* __restrict__ isi, const int* __restrict__ gid,
        float* __restrict__ sums, const int* __restrict__ gstart,
        const int* __restrict__ gend, const float* __restrict__ Wr,
        const float* __restrict__ br, float* __restrict__ out,
        int* __restrict__ done, int N) {
    __shared__ union {
        struct { ushort16 A[128 * 128]; ushort16 W[128 * 128]; } st;
        float Y[128 * YSTRIDE];
    } u;
    __shared__ float ISI[128];
    int t = threadIdx.x;
    int n0 = blockIdx.x * 128;
    {
        int r = t >> 2;
        int k0 = (t & 3) * 32;
        bool valid = (n0 + r) < N;
        const uint4* ga = (const uint4*)((const ushort16*)agg2bf + (size_t)(n0 + r) * 128 + k0);
        const uint4* gw = (const uint4*)(W2T + (size_t)r * 128 + k0);
        #pragma unroll
        for (int q = 0; q < 4; ++q) {
            uint4 va = valid ? ga[q] : uint4{0, 0, 0, 0};
            uint4 vw = gw[q];
            int kg = k0 + q * 8;
            *(uint4*)&u.st.A[r * 128 + (kg ^ SWZB(r))] = va;
            *(uint4*)&u.st.W[r * 128 + (kg ^ SWZB(r))] = vw;
        }
        if (t < 128) ISI[t] = (n0 + t < N) ? isi[n0 + t] : 0.f;
    }
    __syncthreads();
    int w = __builtin_amdgcn_readfirstlane(t >> 6);
    int l = t & 63, l15 = l & 15, lhi = l >> 4;
    int jcol = w * 16 + l15;
    float b2j = b2[jcol];
    f32x4 acc[8] = {};
    #pragma unroll
    for (int kk = 0; kk < 4; ++kk) {
        int kb = kk * 32 + lhi * 8;
        bf16x8 bf = *(bf16x8*)&u.st.W[jcol * 128 + (kb ^ SWZB(jcol))];
        #pragma unroll
        for (int tm = 0; tm < 8; ++tm) {
            int row = tm * 16 + l15;
            bf16x8 af = *(bf16x8*)&u.st.A[row * 128 + (kb ^ SWZB(row))];
            acc[tm] = __builtin_amdgcn_mfma_f32_16x16x32_bf16(af, bf, acc[tm], 0, 0, 0);
        }
    }
    __syncthreads();
    #pragma unroll
    for (int tm = 0; tm < 8; ++tm) {
        #pragma unroll
        for (int i = 0; i < 4; ++i) {
            int m = tm * 16 + lhi * 4 + i;
            u.Y[m * YSTRIDE + jcol] = fmaxf(fmaf(acc[tm][i], ISI[m], b2j), 0.f);
        }
    }
    __syncthreads();
    int j = t & 127;
    int seg = t >> 7;
    float racc = 0.f;
    int cur = -1;
    for (int i = 0; i < 32; ++i) {
        int ln = seg * 32 + i;
        int n = n0 + ln;
        if (n >= N) break;
        float y = u.Y[ln * YSTRIDE + j];
        int g = gid[n];
        if (g != cur) {
            if (cur >= 0) atomicAdd(&sums[cur * N_H + j], racc);
            racc = 0.f;
            cur = g;
        }
        racc += y;
    }
    if (cur >= 0) atomicAdd(&sums[cur * N_H + j], racc);
    // --- fused readout: last block computes out ---
    __threadfence();
    __syncthreads();
    __shared__ int isLast;
    if (t == 0) isLast = (atomicAdd(done, 1) == (int)gridDim.x - 1) ? 1 : 0;
    __syncthreads();
    if (isLast) {
        int lane = t & 63;
        int wv8 = t >> 6;   // 0..7
        for (int g = wv8; g < N_G; g += 8) {
            float c = fmaxf((float)(gend[g] - gstart[g]), 1.f);
            float s0 = __hip_atomic_load(&sums[g * N_H + lane],
                                         __ATOMIC_RELAXED, __HIP_MEMORY_SCOPE_AGENT);
            float s1 = __hip_atomic_load(&sums[g * N_H + lane + 64],
                                         __ATOMIC_RELAXED, __HIP_MEMORY_SCOPE_AGENT);
            float v = (s0 * Wr[lane] + s1 * Wr[lane + 64]) / c;
            #pragma unroll
            for (int off = 32; off > 0; off >>= 1) v += __shfl_down(v, off);
            if (lane == 0) out[g] = v + br[0];
        }
    }
}

static inline size_t align_up(size_t x, size_t a) { return (x + a - 1) & ~(a - 1); }

extern "C" void kernel_launch(void* const* d_in, const int* in_sizes, int n_in,
                              void* d_out, int out_size, void* d_ws, size_t ws_size,
                              hipStream_t stream) {
    const float* h  = (const float*)d_in[0];
    const int* src  = (const int*)d_in[1];
    const int* dst  = (const int*)d_in[2];
    const int* gid  = (const int*)d_in[3];
    const float* W1 = (const float*)d_in[5];
    const float* b1 = (const float*)d_in[6];
    const float* W2 = (const float*)d_in[7];
    const float* b2 = (const float*)d_in[8];
    const float* Wr = (const float*)d_in[9];
    const float* br = (const float*)d_in[10];
    float* out = (float*)d_out;

    int N = in_sizes[0] / N_IN;
    int E = in_sizes[1];
    int nb2 = (N + 255) / 256;          // reduce_norm / scan blocks
    int npp = (N + HP - 1) / HP;
    int ec  = (E + HC - 1) / HC;
    size_t hist_lds = (size_t)npp * 4;  // 100 KB

    char* ws = (char*)d_ws;
    size_t off = 0;
    auto alloc = [&](size_t bytes) -> char* {
        char* p = ws + off;
        off = align_up(off + bytes, 256);
        return p;
    };
    // zeroed region (zeroed by hist_kernel's wprep blocks)
    int*   gstart  = (int*)alloc((size_t)N_G * 4);
    int*   gend    = (int*)alloc((size_t)N_G * 4);
    float* sums    = (float*)alloc((size_t)N_G * N_H * 4);
    int*   done    = (int*)alloc(4);
    size_t zero_bytes = off;
    int zero_words = (int)(zero_bytes / 4);
    // fully-overwritten region
    int*      deg_in  = (int*)alloc((size_t)N * 4);
    float*    iso     = (float*)alloc((size_t)N * 4);
    float*    isi     = (float*)alloc((size_t)N * 4);
    int*      row_ptr = (int*)alloc((size_t)(N + 1) * 4);
    int*      bsum    = (int*)alloc((size_t)512 * 4);
    int*      col     = (int*)alloc((size_t)E * 4);
    uchar8*   hs8     = (uchar8*)alloc((size_t)N * N_IN);         // fp8 scaled h
    uchar8*   h18     = (uchar8*)alloc((size_t)N * N_H);          // fp8 h1s
    ushort16* W1T     = (ushort16*)alloc((size_t)128 * 64 * 2);
    ushort16* W2T     = (ushort16*)alloc((size_t)128 * 128 * 2);
    ushort16* agg1bf  = (ushort16*)alloc((size_t)N * N_IN * 2);   // 12.8 MB
    uint32*   agg2bf  = (uint32*)alloc((size_t)N * 64 * 4);       // 25.6 MB
    // counting-sort metadata aliases the (still-dead) agg buffers
    ushort16* part_cnt = (ushort16*)agg1bf;
    uchar8*   pre      = (uchar8*)agg2bf;

    int sc_blocks = (N * N_IN / 8 + 255) / 256;

    hist_kernel<<<HP * HC + 8, 1024, hist_lds, stream>>>(src, dst, part_cnt,
            W1, W2, W1T, W2T, (int*)d_ws, zero_words, N, E, npp, ec);
    reduce_norm_kernel<<<nb2, 256, 0, stream>>>(part_cnt, pre, gid, iso, isi,
            deg_in, gstart, gend, bsum, N);
    scanw_scaleh_kernel<<<nb2 + sc_blocks, 256, 0, stream>>>(deg_in, bsum, row_ptr,
            h, iso, hs8, nb2, N);
    fill_kernel<<<HP * HC, 1024, hist_lds, stream>>>(src, dst, row_ptr, pre, col, N, E, npp, ec);
    gather1_kernel<<<(N + 3) / 4, 256, 0, stream>>>(hs8, row_ptr, col, (uint32*)agg1bf, N);
    mm1_kernel<<<(N + 127) / 128, 512, 0, stream>>>(agg1bf, W1T, b1, isi, iso, h18, N);
    gather2_kernel<<<(N + 3) / 4, 256, 0, stream>>>(h18, row_ptr, col, agg2bf, N);
    mm2_kernel<<<(N + 127) / 128, 512, 0, stream>>>(agg2bf, W2T, b2, isi, gid, sums,
            gstart, gend, Wr, br, out, done, N);
}

// Round 15
// 177.830 us; speedup vs baseline: 1.5032x; 1.5032x over previous
//
#include <hip/hip_runtime.h>

#define N_IN 64
#define N_H  128
#define N_G  64
#define HP   4    // node partitions (LDS histogram / fill)
#define HC   64   // edge chunks
#define YSTRIDE 132

// XOR swizzle for bf16 LDS tiles, applied to k in groups of 8 bf16 (16B).
#define SWZB(r) (((r) & 7) << 3)

typedef unsigned int   uint32;
typedef unsigned short ushort16;
typedef unsigned char  uchar8;
typedef float floatx2 __attribute__((ext_vector_type(2)));
typedef short bf16x8 __attribute__((ext_vector_type(8)));
typedef float f32x4  __attribute__((ext_vector_type(4)));

#define FP8_SCALE    32.0f
#define FP8_INVSCALE 0.03125f

#if defined(__has_builtin)
#if __has_builtin(__builtin_amdgcn_cvt_pk_f32_fp8) && __has_builtin(__builtin_amdgcn_cvt_pk_fp8_f32)
#define HW_FP8 1
#endif
#endif

__device__ __forceinline__ float bf2f(ushort16 u) {
    union { uint32 i; float f; } x; x.i = ((uint32)u) << 16; return x.f;
}
__device__ __forceinline__ ushort16 f2bf(float f) {   // round-to-nearest-even
    union { float f; uint32 i; } x; x.f = f;
    uint32 r = x.i + 0x7FFFu + ((x.i >> 16) & 1u);
    return (ushort16)(r >> 16);
}

#ifndef HW_FP8
__device__ __forceinline__ uint32 f2e4m3(float x) {
    union { float f; uint32 i; } v; v.f = x;
    uint32 s = (v.i >> 24) & 0x80u;
    uint32 a = v.i & 0x7FFFFFFFu;
    if (a < 0x3C000000u) return s;
    uint32 r = a + 0x0007FFFFu + ((a >> 20) & 1u);
    int e = (int)(r >> 23) - 120;
    if (e <= 0) return s;
    if (e > 15) return s | 0x7Eu;
    return s | ((uint32)e << 3) | ((r >> 20) & 7u);
}
__device__ __forceinline__ floatx2 e4m3word(uint32 u, bool hi) {
    floatx2 o;
    uint32 w = hi ? (u >> 16) : u;
    #pragma unroll
    for (int k = 0; k < 2; ++k) {
        uint32 b = (w >> (8 * k)) & 0xFFu;
        uint32 m = b & 0x7Fu;
        union { uint32 i; float f; } x;
        x.i = ((b & 0x80u) << 24) | ((m << 20) + 0x3C000000u);
        o[k] = m ? x.f : 0.f;
    }
    return o;
}
#endif

__device__ __forceinline__ floatx2 fp8lo(uint32 u) {
#ifdef HW_FP8
    return __builtin_amdgcn_cvt_pk_f32_fp8((int)u, false);
#else
    return e4m3word(u, false);
#endif
}
__device__ __forceinline__ floatx2 fp8hi(uint32 u) {
#ifdef HW_FP8
    return __builtin_amdgcn_cvt_pk_f32_fp8((int)u, true);
#else
    return e4m3word(u, true);
#endif
}

__device__ __forceinline__ uint32 pack4fp8(float o0, float o1, float o2, float o3) {
#ifdef HW_FP8
    int r = __builtin_amdgcn_cvt_pk_fp8_f32(o0, o1, 0, false);
    r     = __builtin_amdgcn_cvt_pk_fp8_f32(o2, o3, r, true);
    return (uint32)r;
#else
    return f2e4m3(o0) | (f2e4m3(o1) << 8) | (f2e4m3(o2) << 16) | (f2e4m3(o3) << 24);
#endif
}

// ---------------- graph prep ----------------
// hist + wprep fused: blocks [0, HP*HC) histogram; blocks >= HP*HC do
// workspace zeroing + W transposes.
__global__ __launch_bounds__(1024) void hist_kernel(const int* __restrict__ src,
        const int* __restrict__ dst, ushort16* __restrict__ part_cnt,
        const float* __restrict__ W1, const float* __restrict__ W2,
        ushort16* __restrict__ W1T, ushort16* __restrict__ W2T,
        int* __restrict__ zbase, int zero_words,
        int N, int E, int npp, int ec) {
    extern __shared__ int cnt[];
    int b = blockIdx.x;
    if (b >= HP * HC) {
        int base = (b - HP * HC) * 1024 + threadIdx.x;
        for (int t = base; t < zero_words; t += 8 * 1024) zbase[t] = 0;
        for (int t = base; t < 128 * 128; t += 8 * 1024) {
            int j = t >> 7, k = t & 127;
            W2T[j * 128 + k] = f2bf(W2[k * 128 + j]);
        }
        for (int t = base; t < 128 * 64; t += 8 * 1024) {
            int j = t >> 6, k = t & 63;
            W1T[j * 64 + k] = f2bf(W1[k * 128 + j]);
        }
        return;
    }
    int p = b & (HP - 1);
    int c = b >> 2;
    int nlo = p * npp;
    int nhi = min(nlo + npp, N);
    int nn = nhi - nlo;
    if (nn <= 0) return;
    int tid = threadIdx.x;
    for (int i = tid; i < nn; i += 1024) cnt[i] = 0;
    __syncthreads();
    int elo = c * ec, ehi = min(elo + ec, E);
    for (int e = elo + tid; e < ehi; e += 1024) {
        int s = src[e];
        unsigned so = (unsigned)(s - nlo);
        if (so < (unsigned)nn) atomicAdd(&cnt[so], 1);
        int d = dst[e];
        unsigned dof = (unsigned)(d - nlo);
        if (dof < (unsigned)nn) atomicAdd(&cnt[dof], 1 << 16);
    }
    __syncthreads();
    for (int i = tid; i < nn; i += 1024) {
        int v = cnt[i];
        part_cnt[(size_t)c * N + nlo + i] =
            (ushort16)((v & 0xFF) | ((v >> 8) & 0xFF00));
    }
}

// reduce_norm + scan_partial fused: also emits per-block deg_in sums (bsum).
__global__ __launch_bounds__(256) void reduce_norm_kernel(const ushort16* __restrict__ part_cnt,
        uchar8* __restrict__ pre, const int* __restrict__ gid,
        float* __restrict__ iso, float* __restrict__ isi, int* __restrict__ deg_in,
        int* __restrict__ gstart, int* __restrict__ gend, int* __restrict__ bsum, int N) {
    int n = blockIdx.x * 256 + threadIdx.x;
    int si = 0;
    if (n < N) {
        int so = 0;
        #pragma unroll
        for (int c = 0; c < HC; ++c) {
            int v = part_cnt[(size_t)c * N + n];
            so += v & 0xFF;
            pre[(size_t)c * N + n] = (uchar8)si;
            si += v >> 8;
        }
        iso[n] = rsqrtf((float)max(so, 1));
        isi[n] = rsqrtf((float)max(si, 1));
        deg_in[n] = si;
        int g = gid[n];
        if (n == 0 || gid[n - 1] != g) gstart[g] = n;
        if (n == N - 1 || gid[n + 1] != g) gend[g] = n + 1;
    }
    int lane = threadIdx.x & 63, wv = threadIdx.x >> 6;
    int s = si;
    #pragma unroll
    for (int off = 1; off < 64; off <<= 1) s += __shfl_xor(s, off);
    __shared__ int ws[4];
    if (lane == 0) ws[wv] = s;
    __syncthreads();
    if (threadIdx.x == 0) bsum[blockIdx.x] = ws[0] + ws[1] + ws[2] + ws[3];
}

// scan_write (with self-computed bsum prefix) + scale_h fused.
__global__ __launch_bounds__(256) void scanw_scaleh_kernel(const int* __restrict__ deg_in,
        const int* __restrict__ bsum, int* __restrict__ row_ptr,
        const float* __restrict__ h, const float* __restrict__ iso,
        uchar8* __restrict__ hs8, int nb2, int N) {
    int b = blockIdx.x;
    int tid = threadIdx.x;
    if (b < nb2) {
        int lane = tid & 63, wv = tid >> 6;
        int acc = 0;
        for (int i = tid; i < b; i += 256) acc += bsum[i];
        #pragma unroll
        for (int off = 1; off < 64; off <<= 1) acc += __shfl_xor(acc, off);
        __shared__ int wsum[4];
        if (lane == 0) wsum[wv] = acc;
        __syncthreads();
        int base = wsum[0] + wsum[1] + wsum[2] + wsum[3];
        int n = b * 256 + tid;
        int v = (n < N) ? deg_in[n] : 0;
        int s = v;
        #pragma unroll
        for (int off = 1; off < 64; off <<= 1) {
            int t2 = __shfl_up(s, off);
            if (lane >= off) s += t2;
        }
        __shared__ int winc[4];
        if (lane == 63) winc[wv] = s;
        __syncthreads();
        int wpre = 0;
        #pragma unroll
        for (int k = 0; k < 4; ++k) wpre += (k < wv) ? winc[k] : 0;
        if (n < N) row_ptr[n] = base + wpre + s - v;
        if (n == N - 1) row_ptr[N] = base + wpre + s;
    } else {
        int t = (b - nb2) * 256 + tid;
        int base = t * 8;
        if (base >= N * N_IN) return;
        int n = base >> 6;
        float sc = iso[n] * FP8_SCALE;
        float4 a = *(const float4*)&h[base];
        float4 bb = *(const float4*)&h[base + 4];
        uint2 pk;
        pk.x = pack4fp8(a.x * sc, a.y * sc, a.z * sc, a.w * sc);
        pk.y = pack4fp8(bb.x * sc, bb.y * sc, bb.z * sc, bb.w * sc);
        *(uint2*)&hs8[base] = pk;
    }
}

__global__ __launch_bounds__(1024) void fill_kernel(const int* __restrict__ src,
        const int* __restrict__ dst, const int* __restrict__ row_ptr,
        const uchar8* __restrict__ pre, int* __restrict__ col,
        int N, int E, int npp, int ec) {
    extern __shared__ int cur[];
    int p = blockIdx.x & (HP - 1);
    int c = blockIdx.x >> 2;
    int nlo = p * npp;
    int nhi = min(nlo + npp, N);
    int nn = nhi - nlo;
    if (nn <= 0) return;
    int tid = threadIdx.x;
    for (int i = tid; i < nn; i += 1024)
        cur[i] = row_ptr[nlo + i] + (int)pre[(size_t)c * N + nlo + i];
    __syncthreads();
    int elo = c * ec, ehi = min(elo + ec, E);
    for (int e = elo + tid; e < ehi; e += 1024) {
        int d = dst[e];
        unsigned off = (unsigned)(d - nlo);
        if (off < (unsigned)nn) {
            int slot = atomicAdd(&cur[off], 1);
            col[slot] = src[e];
        }
    }
}

// ---------------- gathers ----------------
__global__ __launch_bounds__(256) void gather1_kernel(const uchar8* __restrict__ hs8,
        const int* __restrict__ row_ptr, const int* __restrict__ col,
        uint32* __restrict__ agg1w, int N) {
    int wave = __builtin_amdgcn_readfirstlane(threadIdx.x >> 6);
    int lane = threadIdx.x & 63;
    int qd = lane >> 4, l16 = lane & 15;
    int n = blockIdx.x * 4 + wave;
    if (n >= N) return;
    int p0 = row_ptr[n], p1 = row_ptr[n + 1];
    uint32 lofs = (uint32)l16 * 4;
    float a0 = 0.f, a1 = 0.f, a2 = 0.f, a3 = 0.f;
    for (int pb = p0; pb < p1; pb += 64) {
        int cnt = min(64, p1 - pb);
        uint32 cvoff = ((uint32)col[min(pb + lane, p1 - 1)]) << 6;
        int i0 = 0;
        for (; i0 + 16 <= cnt; i0 += 16) {
            uint32 off[4], u[4];
            #pragma unroll
            for (int i = 0; i < 4; ++i)
                off[i] = __shfl(cvoff, i0 + 4 * i + qd);
            #pragma unroll
            for (int i = 0; i < 4; ++i)
                u[i] = *(const uint32*)((const char*)hs8 + (off[i] + lofs));
            #pragma unroll
            for (int i = 0; i < 4; ++i) {
                floatx2 dlo = fp8lo(u[i]), dhi = fp8hi(u[i]);
                a0 += dlo.x; a1 += dlo.y; a2 += dhi.x; a3 += dhi.y;
            }
        }
        if (i0 < cnt) {
            uint32 off[4], u[4];
            float w[4];
            #pragma unroll
            for (int i = 0; i < 4; ++i) {
                int q = i0 + 4 * i + qd;
                off[i] = __shfl(cvoff, min(q, cnt - 1));
                w[i] = (q < cnt) ? 1.f : 0.f;
            }
            #pragma unroll
            for (int i = 0; i < 4; ++i)
                u[i] = *(const uint32*)((const char*)hs8 + (off[i] + lofs));
            #pragma unroll
            for (int i = 0; i < 4; ++i) {
                floatx2 dlo = fp8lo(u[i]), dhi = fp8hi(u[i]);
                a0 = fmaf(dlo.x, w[i], a0);
                a1 = fmaf(dlo.y, w[i], a1);
                a2 = fmaf(dhi.x, w[i], a2);
                a3 = fmaf(dhi.y, w[i], a3);
            }
        }
    }
    a0 += __shfl_xor(a0, 16); a0 += __shfl_xor(a0, 32);
    a1 += __shfl_xor(a1, 16); a1 += __shfl_xor(a1, 32);
    a2 += __shfl_xor(a2, 16); a2 += __shfl_xor(a2, 32);
    a3 += __shfl_xor(a3, 16); a3 += __shfl_xor(a3, 32);
    if (lane < 16) {
        a0 *= FP8_INVSCALE; a1 *= FP8_INVSCALE; a2 *= FP8_INVSCALE; a3 *= FP8_INVSCALE;
        uint32 w0 = (uint32)f2bf(a0) | ((uint32)f2bf(a1) << 16);
        uint32 w1 = (uint32)f2bf(a2) | ((uint32)f2bf(a3) << 16);
        *(uint2*)&agg1w[(size_t)n * 32 + l16 * 2] = uint2{w0, w1};
    }
}

__global__ __launch_bounds__(256) void gather2_kernel(const uchar8* __restrict__ h18,
        const int* __restrict__ row_ptr, const int* __restrict__ col,
        uint32* __restrict__ agg2w, int N) {
    int wave = __builtin_amdgcn_readfirstlane(threadIdx.x >> 6);
    int lane = threadIdx.x & 63;
    int half = lane >> 5, l32 = lane & 31;
    int n = blockIdx.x * 4 + wave;
    if (n >= N) return;
    int p0 = row_ptr[n], p1 = row_ptr[n + 1];
    uint32 lofs = (uint32)l32 * 4;
    float a0 = 0.f, a1 = 0.f, a2 = 0.f, a3 = 0.f;
    for (int pb = p0; pb < p1; pb += 64) {
        int cnt = min(64, p1 - pb);
        uint32 cvoff = ((uint32)col[min(pb + lane, p1 - 1)]) << 7;
        int i0 = 0;
        for (; i0 + 16 <= cnt; i0 += 16) {
            uint32 off[8], u[8];
            #pragma unroll
            for (int i = 0; i < 8; ++i)
                off[i] = __shfl(cvoff, i0 + 2 * i + half);
            #pragma unroll
            for (int i = 0; i < 8; ++i)
                u[i] = *(const uint32*)((const char*)h18 + (off[i] + lofs));
            #pragma unroll
            for (int i = 0; i < 8; ++i) {
                floatx2 dlo = fp8lo(u[i]), dhi = fp8hi(u[i]);
                a0 += dlo.x; a1 += dlo.y; a2 += dhi.x; a3 += dhi.y;
            }
        }
        if (i0 < cnt) {
            uint32 off[8], u[8];
            float w[8];
            #pragma unroll
            for (int i = 0; i < 8; ++i) {
                int q = i0 + 2 * i + half;
                off[i] = __shfl(cvoff, min(q, cnt - 1));
                w[i] = (q < cnt) ? 1.f : 0.f;
            }
            #pragma unroll
            for (int i = 0; i < 8; ++i)
                u[i] = *(const uint32*)((const char*)h18 + (off[i] + lofs));
            #pragma unroll
            for (int i = 0; i < 8; ++i) {
                floatx2 dlo = fp8lo(u[i]), dhi = fp8hi(u[i]);
                a0 = fmaf(dlo.x, w[i], a0);
                a1 = fmaf(dlo.y, w[i], a1);
                a2 = fmaf(dhi.x, w[i], a2);
                a3 = fmaf(dhi.y, w[i], a3);
            }
        }
    }
    a0 += __shfl_xor(a0, 32);
    a1 += __shfl_xor(a1, 32);
    a2 += __shfl_xor(a2, 32);
    a3 += __shfl_xor(a3, 32);
    if (half == 0) {
        a0 *= FP8_INVSCALE; a1 *= FP8_INVSCALE; a2 *= FP8_INVSCALE; a3 *= FP8_INVSCALE;
        uint32 w0 = (uint32)f2bf(a0) | ((uint32)f2bf(a1) << 16);
        uint32 w1 = (uint32)f2bf(a2) | ((uint32)f2bf(a3) << 16);
        *(uint2*)&agg2w[(size_t)n * 64 + l32 * 2] = uint2{w0, w1};
    }
}

// ---------------- MFMA matmuls ----------------
__global__ __launch_bounds__(512) void mm1_kernel(const ushort16* __restrict__ agg1bf,
        const ushort16* __restrict__ W1T, const float* __restrict__ b1,
        const float* __restrict__ isi, const float* __restrict__ iso,
        uchar8* __restrict__ h18, int N) {
    __shared__ union {
        struct { ushort16 A[128 * 64]; ushort16 W[128 * 64]; } st;
        float Y[128 * YSTRIDE];
    } u;
    __shared__ float ISI[128], ISO[128];
    int t = threadIdx.x;
    int n0 = blockIdx.x * 128;
    {
        int r = t >> 2;
        int k0 = (t & 3) * 16;
        bool valid = (n0 + r) < N;
        const uint4* ga = (const uint4*)(agg1bf + (size_t)(n0 + r) * 64 + k0);
        const uint4* gw = (const uint4*)(W1T + (size_t)r * 64 + k0);
        #pragma unroll
        for (int q = 0; q < 2; ++q) {
            uint4 va = valid ? ga[q] : uint4{0, 0, 0, 0};
            uint4 vw = gw[q];
            int kg = k0 + q * 8;
            *(uint4*)&u.st.A[r * 64 + (kg ^ SWZB(r))] = va;
            *(uint4*)&u.st.W[r * 64 + (kg ^ SWZB(r))] = vw;
        }
        if (t < 128) {
            ISI[t] = (n0 + t < N) ? isi[n0 + t] : 0.f;
            ISO[t] = (n0 + t < N) ? iso[n0 + t] * FP8_SCALE : 0.f;
        }
    }
    __syncthreads();
    int w = __builtin_amdgcn_readfirstlane(t >> 6);
    int l = t & 63, l15 = l & 15, lhi = l >> 4;
    int jcol = w * 16 + l15;
    float b1j = b1[jcol];
    f32x4 acc[8] = {};
    #pragma unroll
    for (int kk = 0; kk < 2; ++kk) {
        int kb = kk * 32 + lhi * 8;
        bf16x8 bf = *(bf16x8*)&u.st.W[jcol * 64 + (kb ^ SWZB(jcol))];
        #pragma unroll
        for (int tm = 0; tm < 8; ++tm) {
            int row = tm * 16 + l15;
            bf16x8 af = *(bf16x8*)&u.st.A[row * 64 + (kb ^ SWZB(row))];
            acc[tm] = __builtin_amdgcn_mfma_f32_16x16x32_bf16(af, bf, acc[tm], 0, 0, 0);
        }
    }
    __syncthreads();
    #pragma unroll
    for (int tm = 0; tm < 8; ++tm) {
        #pragma unroll
        for (int i = 0; i < 4; ++i) {
            int m = tm * 16 + lhi * 4 + i;
            u.Y[m * YSTRIDE + jcol] =
                fmaxf(fmaf(acc[tm][i], ISI[m], b1j), 0.f) * ISO[m];
        }
    }
    __syncthreads();
    {
        int r = t >> 2;
        int c0 = (t & 3) * 32;
        if (n0 + r < N) {
            uint32 b[8];
            #pragma unroll
            for (int q = 0; q < 8; ++q) {
                float4 y4 = *(float4*)&u.Y[r * YSTRIDE + c0 + q * 4];
                b[q] = pack4fp8(y4.x, y4.y, y4.z, y4.w);
            }
            uchar8* dstp = h18 + (size_t)(n0 + r) * 128 + c0;
            *(uint4*)dstp        = uint4{b[0], b[1], b[2], b[3]};
            *(uint4*)(dstp + 16) = uint4{b[4], b[5], b[6], b[7]};
        }
    }
}

__global__ __launch_bounds__(512) void mm2_kernel(const uint32* __restrict__ agg2bf,
        const ushort16* __restrict__ W2T, const float* __restrict__ b2,
        const float* __restrict__ isi, const int* __restrict__ gid,
        float* __restrict__ sums, int N) {
    __shared__ union {
        struct { ushort16 A[128 * 128]; ushort16 W[128 * 128]; } st;
        float Y[128 * YSTRIDE];
    } u;
    __shared__ float ISI[128];
    int t = threadIdx.x;
    int n0 = blockIdx.x * 128;
    {
        int r = t >> 2;
        int k0 = (t & 3) * 32;
        bool valid = (n0 + r) < N;
        const uint4* ga = (const uint4*)((const ushort16*)agg2bf + (size_t)(n0 + r) * 128 + k0);
        const uint4* gw = (const uint4*)(W2T + (size_t)r * 128 + k0);
        #pragma unroll
        for (int q = 0; q < 4; ++q) {
            uint4 va = valid ? ga[q] : uint4{0, 0, 0, 0};
            uint4 vw = gw[q];
            int kg = k0 + q * 8;
            *(uint4*)&u.st.A[r * 128 + (kg ^ SWZB(r))] = va;
            *(uint4*)&u.st.W[r * 128 + (kg ^ SWZB(r))] = vw;
        }
        if (t < 128) ISI[t] = (n0 + t < N) ? isi[n0 + t] : 0.f;
    }
    __syncthreads();
    int w = __builtin_amdgcn_readfirstlane(t >> 6);
    int l = t & 63, l15 = l & 15, lhi = l >> 4;
    int jcol = w * 16 + l15;
    float b2j = b2[jcol];
    f32x4 acc[8] = {};
    #pragma unroll
    for (int kk = 0; kk < 4; ++kk) {
        int kb = kk * 32 + lhi * 8;
        bf16x8 bf = *(bf16x8*)&u.st.W[jcol * 128 + (kb ^ SWZB(jcol))];
        #pragma unroll
        for (int tm = 0; tm < 8; ++tm) {
            int row = tm * 16 + l15;
            bf16x8 af = *(bf16x8*)&u.st.A[row * 128 + (kb ^ SWZB(row))];
            acc[tm] = __builtin_amdgcn_mfma_f32_16x16x32_bf16(af, bf, acc[tm], 0, 0, 0);
        }
    }
    __syncthreads();
    #pragma unroll
    for (int tm = 0; tm < 8; ++tm) {
        #pragma unroll
        for (int i = 0; i < 4; ++i) {
            int m = tm * 16 + lhi * 4 + i;
            u.Y[m * YSTRIDE + jcol] = fmaxf(fmaf(acc[tm][i], ISI[m], b2j), 0.f);
        }
    }
    __syncthreads();
    int j = t & 127;
    int seg = t >> 7;
    float racc = 0.f;
    int cur = -1;
    for (int i = 0; i < 32; ++i) {
        int ln = seg * 32 + i;
        int n = n0 + ln;
        if (n >= N) break;
        float y = u.Y[ln * YSTRIDE + j];
        int g = gid[n];
        if (g != cur) {
            if (cur >= 0) atomicAdd(&sums[cur * N_H + j], racc);
            racc = 0.f;
            cur = g;
        }
        racc += y;
    }
    if (cur >= 0) atomicAdd(&sums[cur * N_H + j], racc);
}

__global__ void out_kernel(const float* __restrict__ sums, const int* __restrict__ gstart,
                           const int* __restrict__ gend, const float* __restrict__ Wr,
                           const float* __restrict__ br, float* __restrict__ out) {
    int g = blockIdx.x;
    int j = threadIdx.x;  // 128 threads
    float c = fmaxf((float)(gend[g] - gstart[g]), 1.f);
    float v = sums[g * N_H + j] / c * Wr[j];
    for (int off = 32; off > 0; off >>= 1) v += __shfl_down(v, off);
    __shared__ float part[2];
    if ((threadIdx.x & 63) == 0) part[threadIdx.x >> 6] = v;
    __syncthreads();
    if (threadIdx.x == 0) out[g] = part[0] + part[1] + br[0];
}

static inline size_t align_up(size_t x, size_t a) { return (x + a - 1) & ~(a - 1); }

extern "C" void kernel_launch(void* const* d_in, const int* in_sizes, int n_in,
                              void* d_out, int out_size, void* d_ws, size_t ws_size,
                              hipStream_t stream) {
    const float* h  = (const float*)d_in[0];
    const int* src  = (const int*)d_in[1];
    const int* dst  = (const int*)d_in[2];
    const int* gid  = (const int*)d_in[3];
    const float* W1 = (const float*)d_in[5];
    const float* b1 = (const float*)d_in[6];
    const float* W2 = (const float*)d_in[7];
    const float* b2 = (const float*)d_in[8];
    const float* Wr = (const float*)d_in[9];
    const float* br = (const float*)d_in[10];
    float* out = (float*)d_out;

    int N = in_sizes[0] / N_IN;
    int E = in_sizes[1];
    int nb2 = (N + 255) / 256;
    int npp = (N + HP - 1) / HP;
    int ec  = (E + HC - 1) / HC;
    size_t hist_lds = (size_t)npp * 4;  // 100 KB

    char* ws = (char*)d_ws;
    size_t off = 0;
    auto alloc = [&](size_t bytes) -> char* {
        char* p = ws + off;
        off = align_up(off + bytes, 256);
        return p;
    };
    // zeroed region (zeroed by hist_kernel's wprep blocks)
    int*   gstart  = (int*)alloc((size_t)N_G * 4);
    int*   gend    = (int*)alloc((size_t)N_G * 4);
    float* sums    = (float*)alloc((size_t)N_G * N_H * 4);
    size_t zero_bytes = off;
    int zero_words = (int)(zero_bytes / 4);
    // fully-overwritten region
    int*      deg_in  = (int*)alloc((size_t)N * 4);
    float*    iso     = (float*)alloc((size_t)N * 4);
    float*    isi     = (float*)alloc((size_t)N * 4);
    int*      row_ptr = (int*)alloc((size_t)(N + 1) * 4);
    int*      bsum    = (int*)alloc((size_t)512 * 4);
    int*      col     = (int*)alloc((size_t)E * 4);
    uchar8*   hs8     = (uchar8*)alloc((size_t)N * N_IN);         // fp8 scaled h
    uchar8*   h18     = (uchar8*)alloc((size_t)N * N_H);          // fp8 h1s
    ushort16* W1T     = (ushort16*)alloc((size_t)128 * 64 * 2);
    ushort16* W2T     = (ushort16*)alloc((size_t)128 * 128 * 2);
    ushort16* agg1bf  = (ushort16*)alloc((size_t)N * N_IN * 2);   // 12.8 MB
    uint32*   agg2bf  = (uint32*)alloc((size_t)N * 64 * 4);       // 25.6 MB
    // counting-sort metadata aliases the (still-dead) agg buffers
    ushort16* part_cnt = (ushort16*)agg1bf;
    uchar8*   pre      = (uchar8*)agg2bf;

    int sc_blocks = (N * N_IN / 8 + 255) / 256;

    hist_kernel<<<HP * HC + 8, 1024, hist_lds, stream>>>(src, dst, part_cnt,
            W1, W2, W1T, W2T, (int*)d_ws, zero_words, N, E, npp, ec);
    reduce_norm_kernel<<<nb2, 256, 0, stream>>>(part_cnt, pre, gid, iso, isi,
            deg_in, gstart, gend, bsum, N);
    scanw_scaleh_kernel<<<nb2 + sc_blocks, 256, 0, stream>>>(deg_in, bsum, row_ptr,
            h, iso, hs8, nb2, N);
    fill_kernel<<<HP * HC, 1024, hist_lds, stream>>>(src, dst, row_ptr, pre, col, N, E, npp, ec);
    gather1_kernel<<<(N + 3) / 4, 256, 0, stream>>>(hs8, row_ptr, col, (uint32*)agg1bf, N);
    mm1_kernel<<<(N + 127) / 128, 512, 0, stream>>>(agg1bf, W1T, b1, isi, iso, h18, N);
    gather2_kernel<<<(N + 3) / 4, 256, 0, stream>>>(h18, row_ptr, col, agg2bf, N);
    mm2_kernel<<<(N + 127) / 128, 512, 0, stream>>>(agg2bf, W2T, b2, isi, gid, sums, N);
    out_kernel<<<N_G, N_H, 0, stream>>>(sums, gstart, gend, Wr, br, out);
}